// Round 4
// baseline (349.448 us; speedup 1.0000x reference)
//
#include <hip/hip_runtime.h>
#include <hip/hip_bf16.h>

typedef __bf16 bf16_t;
typedef __bf16 bf16x2 __attribute__((ext_vector_type(2)));
typedef __bf16 bf16x8 __attribute__((ext_vector_type(8)));
typedef float f32x4 __attribute__((ext_vector_type(4)));
typedef float f32x16 __attribute__((ext_vector_type(16)));
typedef unsigned int u32;
typedef unsigned long long u64;

#define S_LEN 2048
#define DM 1024
#define NH 16
#define DK 64
#define M_ROWS 4096
#define SCALE_LOG2E 0.1803368801111204f /* 0.125 * log2(e) */

// 64-col bf16 tile image: 8 chunks of 8 elems; phys chunk = chunk ^ (row&7).
__device__ __forceinline__ int sw_off(int row, int col) {
  return row * 64 + ((((col >> 3) ^ row) & 7) << 3) + (col & 7);
}

__device__ __forceinline__ bf16x8 cvt8(const float4& a, const float4& b) {
  bf16x8 v;
  v[0] = (__bf16)a.x; v[1] = (__bf16)a.y; v[2] = (__bf16)a.z; v[3] = (__bf16)a.w;
  v[4] = (__bf16)b.x; v[5] = (__bf16)b.y; v[6] = (__bf16)b.z; v[7] = (__bf16)b.w;
  return v;
}

__device__ __forceinline__ void glds16(const bf16_t* g, bf16_t* l) {
  __builtin_amdgcn_global_load_lds(
      (const __attribute__((address_space(1))) void*)g,
      (__attribute__((address_space(3))) void*)l, 16, 0, 0);
}

// sign-extend bit c of m -> 0xFFFFFFFF or 0
__device__ __forceinline__ u32 bitmask32(u32 m, int c) {
  return (u32)(((int)(m << (31 - c))) >> 31);
}
__device__ __forceinline__ float mand(float p, u32 e) {
  return __builtin_bit_cast(float, __builtin_bit_cast(u32, p) & e);
}
__device__ __forceinline__ u32 pack2(float lo, float hi) {
#if __has_builtin(__builtin_amdgcn_cvt_pk_bf16_f32)
  bf16x2 r = __builtin_amdgcn_cvt_pk_bf16_f32(lo, hi);
  return __builtin_bit_cast(u32, r);
#else
  union { __bf16 h[2]; u32 u; } x;
  x.h[0] = (__bf16)lo; x.h[1] = (__bf16)hi;
  return x.u;
#endif
}

union U4B { uint4 u; bf16x8 v; };

// mask int32 [B,1,S,S] -> column-packed u64: mbT[b][qw][key], bit i = mask[b][qw*64+i][key]
__global__ __launch_bounds__(256) void pack_maskT(
    const int* __restrict__ mask, u64* __restrict__ mbT)
{
  const int g = blockIdx.x * 256 + threadIdx.x;  // 32768: b(1)|qw(5)|key4(9)
  const int key4 = (g & 511) * 4;
  const int qw = (g >> 9) & 31;
  const int b = g >> 14;
  const int* src = &mask[((size_t)b * S_LEN + qw * 64) * S_LEN + key4];
  u64 b0 = 0, b1 = 0, b2 = 0, b3 = 0;
  #pragma unroll 8
  for (int i = 0; i < 64; ++i) {
    const int4 v = *(const int4*)&src[(size_t)i * S_LEN];
    b0 |= (u64)(v.x != 0) << i;
    b1 |= (u64)(v.y != 0) << i;
    b2 |= (u64)(v.z != 0) << i;
    b3 |= (u64)(v.w != 0) << i;
  }
  u64* dst = &mbT[((size_t)b * 32 + qw) * S_LEN + key4];
  dst[0] = b0; dst[1] = b1; dst[2] = b2; dst[3] = b3;
}

// q,k,v fp32 -> Xb bf16 [3][4096][1024]
__global__ __launch_bounds__(256) void cvt_inputs(
    const float* __restrict__ q, const float* __restrict__ k,
    const float* __restrict__ v, bf16_t* __restrict__ Xb)
{
  const int z = blockIdx.y;
  const float* __restrict__ src = (z == 0) ? q : ((z == 1) ? k : v);
  const size_t idx = ((size_t)blockIdx.x * 256 + threadIdx.x) * 8;
  const float4 a = *(const float4*)&src[idx];
  const float4 b = *(const float4*)&src[idx + 4];
  *(bf16x8*)&Xb[(size_t)z * M_ROWS * DM + idx] = cvt8(a, b);
}

// W fp32 [k][n] -> Wt bf16 [n][k]
__global__ __launch_bounds__(256) void transw_kernel(
    const float* __restrict__ Wq, const float* __restrict__ Wk,
    const float* __restrict__ Wv, const float* __restrict__ Wo,
    bf16_t* __restrict__ Wt)
{
  const int z = blockIdx.z;
  const float* __restrict__ W = (z == 0) ? Wq : ((z == 1) ? Wk : ((z == 2) ? Wv : Wo));
  bf16_t* __restrict__ out = Wt + (size_t)z * DM * DM;
  __shared__ float tile[64][65];
  const int tx = threadIdx.x & 31, ty = threadIdx.x >> 5;
  const int k0 = blockIdx.x * 64, n0 = blockIdx.y * 64;
  #pragma unroll
  for (int j = 0; j < 8; ++j) {
    const float2 v = *(const float2*)&W[(size_t)(k0 + ty + 8 * j) * DM + n0 + tx * 2];
    tile[ty + 8 * j][tx * 2] = v.x;
    tile[ty + 8 * j][tx * 2 + 1] = v.y;
  }
  __syncthreads();
  #pragma unroll
  for (int j = 0; j < 8; ++j) {
    const int a = ty + 8 * j;
    bf16x2 p;
    p[0] = (__bf16)tile[tx * 2][a];
    p[1] = (__bf16)tile[tx * 2 + 1][a];
    *(bf16x2*)&out[(size_t)(n0 + a) * DM + k0 + tx * 2] = p;
  }
}

// 128x128 BK=32 BT-GEMM core (m97 structure, global_load_lds width 16)
__device__ __forceinline__ void gemm_core(
    const bf16_t* __restrict__ A, const bf16_t* __restrict__ Bt,
    f32x4 (&acc)[4][4])
{
  __shared__ __align__(16) bf16_t As[128 * 32];
  __shared__ __align__(16) bf16_t Bs[128 * 32];
  const int t = threadIdx.x, w = t >> 6, L = t & 63, quad = L >> 4, l16 = L & 15;
  const int m0 = blockIdx.x * 128, n0 = blockIdx.y * 128;
  const int mb = 64 * (w & 1), nb = 64 * (w >> 1);
  const int rowS = t >> 2, subS = (t & 3) * 8;

  for (int k0 = 0; k0 < DM; k0 += 32) {
    __syncthreads();
    glds16(&A[(size_t)(m0 + rowS) * DM + k0 + subS],       &As[t * 8]);
    glds16(&A[(size_t)(m0 + 64 + rowS) * DM + k0 + subS],  &As[2048 + t * 8]);
    glds16(&Bt[(size_t)(n0 + rowS) * DM + k0 + subS],      &Bs[t * 8]);
    glds16(&Bt[(size_t)(n0 + 64 + rowS) * DM + k0 + subS], &Bs[2048 + t * 8]);
    __syncthreads();
    bf16x8 af[4], bfr[4];
    #pragma unroll
    for (int mt = 0; mt < 4; ++mt)
      af[mt] = *(const bf16x8*)&As[(mb + 16 * mt + l16) * 32 + quad * 8];
    #pragma unroll
    for (int ct = 0; ct < 4; ++ct)
      bfr[ct] = *(const bf16x8*)&Bs[(nb + 16 * ct + l16) * 32 + quad * 8];
    #pragma unroll
    for (int mt = 0; mt < 4; ++mt)
      #pragma unroll
      for (int ct = 0; ct < 4; ++ct)
        acc[mt][ct] = __builtin_amdgcn_mfma_f32_16x16x32_bf16(af[mt], bfr[ct], acc[mt][ct], 0, 0, 0);
  }
}

// z=0: Q plain, pre-scaled by SCALE_LOG2E. z=1: K swizzled tile images. z=2: V plain.
__global__ __launch_bounds__(256) void gemm_qkv(
    const bf16_t* __restrict__ Xb, const bf16_t* __restrict__ Wt,
    const float* __restrict__ bq, const float* __restrict__ bk,
    const float* __restrict__ bv,
    bf16_t* __restrict__ Qp, bf16_t* __restrict__ Ksw, bf16_t* __restrict__ Vpl)
{
  const int z = blockIdx.z;
  const float* __restrict__ bias = (z == 0) ? bq : ((z == 1) ? bk : bv);
  f32x4 acc[4][4] = {};
  gemm_core(Xb + (size_t)z * M_ROWS * DM, Wt + (size_t)z * DM * DM, acc);

  const int t = threadIdx.x, w = t >> 6, L = t & 63, quad = L >> 4, l16 = L & 15;
  const int m0 = blockIdx.x * 128, n0 = blockIdx.y * 128;
  const int mb = 64 * (w & 1), nb = 64 * (w >> 1);
  #pragma unroll
  for (int mt = 0; mt < 4; ++mt)
    #pragma unroll
    for (int ct = 0; ct < 4; ++ct)
      #pragma unroll
      for (int r = 0; r < 4; ++r) {
        const int row = m0 + mb + 16 * mt + quad * 4 + r;
        const int n = n0 + nb + 16 * ct + l16;
        float val = acc[mt][ct][r] + bias[n];
        if (z == 0) {
          Qp[(size_t)row * DM + n] = (__bf16)(val * SCALE_LOG2E);
        } else if (z == 2) {
          Vpl[(size_t)row * DM + n] = (__bf16)val;
        } else {
          const int b_ = row >> 11, s = row & 2047, h = n >> 6, d = n & 63;
          const int bh = b_ * NH + h;
          Ksw[((size_t)bh * 32 + (s >> 6)) * 4096 + sw_off(s & 63, d)] = (__bf16)val;
        }
      }
}

// Vpl [B,S,DM] -> Vt_sw swizzled [bh][tile][image of V^T 64dv x 64key]
__global__ __launch_bounds__(256) void transpV(
    const bf16_t* __restrict__ Vpl, bf16_t* __restrict__ Vt_sw)
{
  __shared__ bf16_t Tr[64 * 72];
  const int t = threadIdx.x;
  const int key0 = blockIdx.x * 64;
  const int bh = blockIdx.y, b = bh >> 4, h = bh & 15;
  const int r = t >> 2, c = (t & 3) * 16;
  const bf16_t* src = &Vpl[(size_t)(b * S_LEN + key0 + r) * DM + h * DK + c];
  const bf16x8 v0 = *(const bf16x8*)src;
  const bf16x8 v1 = *(const bf16x8*)(src + 8);
  #pragma unroll
  for (int j = 0; j < 8; ++j) {
    Tr[r * 72 + c + j] = v0[j];
    Tr[r * 72 + c + 8 + j] = v1[j];
  }
  __syncthreads();
  const int dv = t >> 2, kc = (t & 3) * 16;
  bf16_t ov[16];
  #pragma unroll
  for (int j = 0; j < 16; ++j) ov[j] = Tr[(kc + j) * 72 + dv];
  bf16_t* dst = &Vt_sw[((size_t)bh * 32 + blockIdx.x) * 4096];
  *(bf16x8*)&dst[sw_off(dv, kc)]     = *(bf16x8*)&ov[0];
  *(bf16x8*)&dst[sw_off(dv, kc + 8)] = *(bf16x8*)&ov[8];
}

// Flash attention, split-K=2. Q-tile 128 (wave owns 32 q-rows, Q in registers),
// K-tile 64, 32x32x16 MFMA, unbiased exp2 softmax, AND-masking, l via MFMA(ones).
// P stored as packed q-row-pair dwords (conflict-free b32 writes, perm unpack).
__global__ __launch_bounds__(256, 4) void attn_kernel(
    const bf16_t* __restrict__ Qp, const bf16_t* __restrict__ Ksw,
    const bf16_t* __restrict__ Vt_sw, const u64* __restrict__ mbT,
    bf16_t* __restrict__ Of, float* __restrict__ Lf)
{
  __shared__ __align__(16) bf16_t Ks[4096];
  __shared__ __align__(16) bf16_t Vts[4096];
  __shared__ __align__(16) u32 Psd[4096];  // [qpair][64 key dwords], chunk-swizzled

  const int t = threadIdx.x, w = t >> 6, L = t & 63;
  const int l31 = L & 31, h5 = L >> 5;
  const int q0 = blockIdx.x * 128;
  const int bh = blockIdx.y, b = bh >> 4, h = bh & 15;
  const int split = blockIdx.z;
  const int xk3 = (l31 & 7) << 3;
  const u32 sel = (l31 & 1) ? 0x07060302u : 0x05040100u;

  // Q fragments in registers (A-operand layout), pre-scaled in gemm_qkv
  bf16x8 qf[4];
  {
    const bf16_t* qrow = &Qp[((size_t)(b * S_LEN) + q0 + 32 * w + l31) * DM + h * DK + 8 * h5];
    #pragma unroll
    for (int ks = 0; ks < 4; ++ks) qf[ks] = *(const bf16x8*)&qrow[16 * ks];
  }

  bf16x8 ones;
  #pragma unroll
  for (int j = 0; j < 8; ++j) ones[j] = (__bf16)1.0f;

  const int qw = (q0 >> 6) + (w >> 1);
  const size_t mrow = ((size_t)b * 32 + qw) * S_LEN;
  const int bitc = 32 * (w & 1) + 4 * h5;

  const bf16_t* Kbase = Ksw + (size_t)bh * 32 * 4096;
  const bf16_t* Vbase = Vt_sw + (size_t)bh * 32 * 4096;

  f32x16 O0 = {}, O1 = {}, Lacc = {};

  for (int kt = split * 16; kt < split * 16 + 16; ++kt) {
    __syncthreads();
    glds16(Kbase + (size_t)kt * 4096 + t * 8,        &Ks[t * 8]);
    glds16(Kbase + (size_t)kt * 4096 + 2048 + t * 8, &Ks[2048 + t * 8]);
    glds16(Vbase + (size_t)kt * 4096 + t * 8,        &Vts[t * 8]);
    glds16(Vbase + (size_t)kt * 4096 + 2048 + t * 8, &Vts[2048 + t * 8]);
    const u64 mq0 = mbT[mrow + kt * 64 + l31];
    const u64 mq1 = mbT[mrow + kt * 64 + 32 + l31];
    __syncthreads();  // barrier waits vmcnt(0): glds landed

    // S = Q K^T (scores already in log2 domain)
    f32x16 s0 = {}, s1 = {};
    #pragma unroll
    for (int ks = 0; ks < 4; ++ks) {
      const int ko = ((2 * ks + h5) << 3) ^ xk3;
      const bf16x8 kb0 = *(const bf16x8*)&Ks[l31 * 64 + ko];
      const bf16x8 kb1 = *(const bf16x8*)&Ks[(32 + l31) * 64 + ko];
      s0 = __builtin_amdgcn_mfma_f32_32x32x16_bf16(qf[ks], kb0, s0, 0, 0, 0);
      s1 = __builtin_amdgcn_mfma_f32_32x32x16_bf16(qf[ks], kb1, s1, 0, 0, 0);
    }

    // softmax: p = exp2(s), mask via sign-extended-bit AND, pack q-row pairs
    const u32 m32_0 = (u32)(mq0 >> bitc);
    const u32 m32_1 = (u32)(mq1 >> bitc);
    #pragma unroll
    for (int rp = 0; rp < 16; rp += 2) {
      const int c = (rp & 3) + 8 * (rp >> 2);  // even
      const int qp = 16 * w + (c >> 1) + 2 * h5;
      float p00 = mand(__builtin_exp2f(s0[rp]),     bitmask32(m32_0, c));
      float p01 = mand(__builtin_exp2f(s0[rp + 1]), bitmask32(m32_0, c + 1));
      float p10 = mand(__builtin_exp2f(s1[rp]),     bitmask32(m32_1, c));
      float p11 = mand(__builtin_exp2f(s1[rp + 1]), bitmask32(m32_1, c + 1));
      Psd[qp * 64 + ((((l31 >> 3) ^ qp) & 7) << 3) + (l31 & 7)]         = pack2(p00, p01);
      Psd[qp * 64 + (((((l31 >> 3) + 4) ^ qp) & 7) << 3) + (l31 & 7)]   = pack2(p10, p11);
    }

    // O += P V ; Lacc += P @ ones  (Ps q-pairs wave-private: no barrier)
    const int qpr = 16 * w + (l31 >> 1);
    #pragma unroll
    for (int kk = 0; kk < 4; ++kk) {
      const int ch = ((2 * kk + h5) ^ qpr) & 7;
      const uint4 lo = *(const uint4*)&Psd[qpr * 64 + ch * 8];
      const uint4 hi = *(const uint4*)&Psd[qpr * 64 + ch * 8 + 4];
      U4B af;
      af.u.x = __builtin_amdgcn_perm(lo.y, lo.x, sel);
      af.u.y = __builtin_amdgcn_perm(lo.w, lo.z, sel);
      af.u.z = __builtin_amdgcn_perm(hi.y, hi.x, sel);
      af.u.w = __builtin_amdgcn_perm(hi.w, hi.z, sel);
      const int vo = ((2 * kk + h5) << 3) ^ xk3;
      const bf16x8 vb0 = *(const bf16x8*)&Vts[l31 * 64 + vo];
      const bf16x8 vb1 = *(const bf16x8*)&Vts[(32 + l31) * 64 + vo];
      O0 = __builtin_amdgcn_mfma_f32_32x32x16_bf16(af.v, vb0, O0, 0, 0, 0);
      O1 = __builtin_amdgcn_mfma_f32_32x32x16_bf16(af.v, vb1, O1, 0, 0, 0);
      Lacc = __builtin_amdgcn_mfma_f32_32x32x16_bf16(af.v, ones, Lacc, 0, 0, 0);
    }
  }

  // epilogue: unnormalized partial O (bf16) + partial l
  #pragma unroll
  for (int r = 0; r < 16; ++r) {
    const int row = q0 + 32 * w + (r & 3) + 8 * (r >> 2) + 4 * h5;
    const size_t obase = (((size_t)split * M_ROWS) + b * S_LEN + row) * DM + h * DK;
    Of[obase + l31]      = (__bf16)O0[r];
    Of[obase + 32 + l31] = (__bf16)O1[r];
    if (l31 == 0)
      Lf[((size_t)split * M_ROWS + b * S_LEN + row) * NH + h] = Lacc[r];
  }
}

// ctx = (O0 + O1) / (l0 + l1)
__global__ __launch_bounds__(256) void merge_kernel(
    const bf16_t* __restrict__ Of, const float* __restrict__ Lf,
    bf16_t* __restrict__ ctx)
{
  const size_t idx = ((size_t)blockIdx.x * 256 + threadIdx.x) * 8;
  const int row = (int)(idx >> 10);
  const int h = (int)((idx >> 6) & 15);
  const float l = Lf[(size_t)row * NH + h] + Lf[(size_t)M_ROWS * NH + (size_t)row * NH + h];
  const float inv = 1.0f / l;
  const bf16x8 o0 = *(const bf16x8*)&Of[idx];
  const bf16x8 o1 = *(const bf16x8*)&Of[(size_t)M_ROWS * DM + idx];
  bf16x8 r;
  #pragma unroll
  for (int j = 0; j < 8; ++j)
    r[j] = (__bf16)(((float)o0[j] + (float)o1[j]) * inv);
  *(bf16x8*)&ctx[idx] = r;
}

// out = ctx @ Wo^T + bo -> fp32
__global__ __launch_bounds__(256) void gemm_out(
    const bf16_t* __restrict__ ctx, const bf16_t* __restrict__ Wto,
    const float* __restrict__ bo, float* __restrict__ out)
{
  f32x4 acc[4][4] = {};
  gemm_core(ctx, Wto, acc);
  const int t = threadIdx.x, w = t >> 6, L = t & 63, quad = L >> 4, l16 = L & 15;
  const int m0 = blockIdx.x * 128, n0 = blockIdx.y * 128;
  const int mb = 64 * (w & 1), nb = 64 * (w >> 1);
  #pragma unroll
  for (int mt = 0; mt < 4; ++mt)
    #pragma unroll
    for (int ct = 0; ct < 4; ++ct)
      #pragma unroll
      for (int r = 0; r < 4; ++r) {
        const int row = m0 + mb + 16 * mt + quad * 4 + r;
        const int n = n0 + nb + 16 * ct + l16;
        out[(size_t)row * DM + n] = acc[mt][ct][r] + bo[n];
      }
}

extern "C" void kernel_launch(void* const* d_in, const int* in_sizes, int n_in,
                              void* d_out, int out_size, void* d_ws, size_t ws_size,
                              hipStream_t stream) {
  const float* q  = (const float*)d_in[0];
  const float* k  = (const float*)d_in[1];
  const float* v  = (const float*)d_in[2];
  const int* mask = (const int*)d_in[3];
  const float* Wq = (const float*)d_in[4];
  const float* bq = (const float*)d_in[5];
  const float* Wk = (const float*)d_in[6];
  const float* bk = (const float*)d_in[7];
  const float* Wv = (const float*)d_in[8];
  const float* bv = (const float*)d_in[9];
  const float* Wo = (const float*)d_in[10];
  const float* bo = (const float*)d_in[11];
  float* out = (float*)d_out;

  const size_t SLICE = (size_t)M_ROWS * DM;  // 4.19M bf16 elems = 8 MB
  bf16_t* ws_b = (bf16_t*)d_ws;
  bf16_t* Xb    = ws_b;                // 3 SLICE; dead after gemm_qkv
  bf16_t* Qp    = ws_b + 3 * SLICE;    // plain, pre-scaled
  bf16_t* Ksw   = ws_b + 4 * SLICE;    // swizzled K tiles
  bf16_t* Vpl   = ws_b + 5 * SLICE;    // plain V
  bf16_t* Wt    = ws_b + 6 * SLICE;    // 4x1024x1024 = 1 SLICE
  u64* mbT      = (u64*)(ws_b + 7 * SLICE);           // 1 MB
  float* Lf     = (float*)((char*)mbT + (1 << 20));   // 512 KB
  bf16_t* Of    = ws_b;                // 2 SLICE, alias Xb slices 0-1
  bf16_t* Vt_sw = ws_b + 2 * SLICE;    // alias Xb slice 2
  bf16_t* ctx   = ws_b + 2 * SLICE;    // alias Vt_sw (dead at merge time)

  pack_maskT<<<dim3(128), dim3(256), 0, stream>>>(mask, mbT);
  cvt_inputs<<<dim3(2048, 3), dim3(256), 0, stream>>>(q, k, v, Xb);
  transw_kernel<<<dim3(16, 16, 4), dim3(256), 0, stream>>>(Wq, Wk, Wv, Wo, Wt);
  gemm_qkv<<<dim3(32, 8, 3), dim3(256), 0, stream>>>(Xb, Wt, bq, bk, bv, Qp, Ksw, Vpl);
  transpV<<<dim3(32, 32), dim3(256), 0, stream>>>(Vpl, Vt_sw);
  attn_kernel<<<dim3(16, 32, 2), dim3(256), 0, stream>>>(Qp, Ksw, Vt_sw, mbT, Of, Lf);
  merge_kernel<<<dim3(2048), dim3(256), 0, stream>>>(Of, Lf, ctx);
  gemm_out<<<dim3(32, 8), dim3(256), 0, stream>>>(ctx, Wt + (size_t)3 * DM * DM, bo, out);
}

// Round 5
// 303.316 us; speedup vs baseline: 1.1521x; 1.1521x over previous
//
#include <hip/hip_runtime.h>
#include <hip/hip_bf16.h>

typedef __bf16 bf16_t;
typedef __bf16 bf16x2 __attribute__((ext_vector_type(2)));
typedef __bf16 bf16x8 __attribute__((ext_vector_type(8)));
typedef float f32x4 __attribute__((ext_vector_type(4)));
typedef float f32x16 __attribute__((ext_vector_type(16)));
typedef unsigned int u32;
typedef unsigned long long u64;

#define S_LEN 2048
#define DM 1024
#define NH 16
#define DK 64
#define M_ROWS 4096
#define SCALE_LOG2E 0.1803368801111204f /* 0.125 * log2(e) */

// 64-col bf16 tile image: 8 chunks of 8 elems; phys chunk = chunk ^ (row&7).
__device__ __forceinline__ int sw_off(int row, int col) {
  return row * 64 + ((((col >> 3) ^ row) & 7) << 3) + (col & 7);
}

__device__ __forceinline__ bf16x8 cvt8(const float4& a, const float4& b) {
  bf16x8 v;
  v[0] = (__bf16)a.x; v[1] = (__bf16)a.y; v[2] = (__bf16)a.z; v[3] = (__bf16)a.w;
  v[4] = (__bf16)b.x; v[5] = (__bf16)b.y; v[6] = (__bf16)b.z; v[7] = (__bf16)b.w;
  return v;
}

__device__ __forceinline__ void glds16(const bf16_t* g, bf16_t* l) {
  __builtin_amdgcn_global_load_lds(
      (const __attribute__((address_space(1))) void*)g,
      (__attribute__((address_space(3))) void*)l, 16, 0, 0);
}

// sign-extended single bit c of m (0 or 0xFFFFFFFF), one v_bfe_i32
__device__ __forceinline__ u32 sbit(u32 m, int c) {
#if __has_builtin(__builtin_amdgcn_sbfe)
  return (u32)__builtin_amdgcn_sbfe((int)m, c, 1);
#else
  return (u32)(((int)(m << (31 - c))) >> 31);
#endif
}
__device__ __forceinline__ float mand(float p, u32 e) {
  return __builtin_bit_cast(float, __builtin_bit_cast(u32, p) & e);
}
__device__ __forceinline__ u32 pack2(float lo, float hi) {
#if __has_builtin(__builtin_amdgcn_cvt_pk_bf16_f32)
  bf16x2 r = __builtin_amdgcn_cvt_pk_bf16_f32(lo, hi);
  return __builtin_bit_cast(u32, r);
#else
  union { __bf16 h[2]; u32 u; } x;
  x.h[0] = (__bf16)lo; x.h[1] = (__bf16)hi;
  return x.u;
#endif
}

union U4B { uint4 u; bf16x8 v; };

// mask int32 [B,1,S,S] -> column-packed u64: mbT[b][qw][key], bit i = mask[b][qw*64+i][key]
__global__ __launch_bounds__(256) void pack_maskT(
    const int* __restrict__ mask, u64* __restrict__ mbT)
{
  const int g = blockIdx.x * 256 + threadIdx.x;  // 32768: b(1)|qw(5)|key4(9)
  const int key4 = (g & 511) * 4;
  const int qw = (g >> 9) & 31;
  const int b = g >> 14;
  const int* src = &mask[((size_t)b * S_LEN + qw * 64) * S_LEN + key4];
  u64 b0 = 0, b1 = 0, b2 = 0, b3 = 0;
  #pragma unroll 8
  for (int i = 0; i < 64; ++i) {
    const int4 v = *(const int4*)&src[(size_t)i * S_LEN];
    b0 |= (u64)(v.x != 0) << i;
    b1 |= (u64)(v.y != 0) << i;
    b2 |= (u64)(v.z != 0) << i;
    b3 |= (u64)(v.w != 0) << i;
  }
  u64* dst = &mbT[((size_t)b * 32 + qw) * S_LEN + key4];
  dst[0] = b0; dst[1] = b1; dst[2] = b2; dst[3] = b3;
}

// q,k,v fp32 -> Xb bf16 [3][4096][1024]
__global__ __launch_bounds__(256) void cvt_inputs(
    const float* __restrict__ q, const float* __restrict__ k,
    const float* __restrict__ v, bf16_t* __restrict__ Xb)
{
  const int z = blockIdx.y;
  const float* __restrict__ src = (z == 0) ? q : ((z == 1) ? k : v);
  const size_t idx = ((size_t)blockIdx.x * 256 + threadIdx.x) * 8;
  const float4 a = *(const float4*)&src[idx];
  const float4 b = *(const float4*)&src[idx + 4];
  *(bf16x8*)&Xb[(size_t)z * M_ROWS * DM + idx] = cvt8(a, b);
}

// W fp32 [k][n] -> Wt bf16 [n][k]
__global__ __launch_bounds__(256) void transw_kernel(
    const float* __restrict__ Wq, const float* __restrict__ Wk,
    const float* __restrict__ Wv, const float* __restrict__ Wo,
    bf16_t* __restrict__ Wt)
{
  const int z = blockIdx.z;
  const float* __restrict__ W = (z == 0) ? Wq : ((z == 1) ? Wk : ((z == 2) ? Wv : Wo));
  bf16_t* __restrict__ out = Wt + (size_t)z * DM * DM;
  __shared__ float tile[64][65];
  const int tx = threadIdx.x & 31, ty = threadIdx.x >> 5;
  const int k0 = blockIdx.x * 64, n0 = blockIdx.y * 64;
  #pragma unroll
  for (int j = 0; j < 8; ++j) {
    const float2 v = *(const float2*)&W[(size_t)(k0 + ty + 8 * j) * DM + n0 + tx * 2];
    tile[ty + 8 * j][tx * 2] = v.x;
    tile[ty + 8 * j][tx * 2 + 1] = v.y;
  }
  __syncthreads();
  #pragma unroll
  for (int j = 0; j < 8; ++j) {
    const int a = ty + 8 * j;
    bf16x2 p;
    p[0] = (__bf16)tile[tx * 2][a];
    p[1] = (__bf16)tile[tx * 2 + 1][a];
    *(bf16x2*)&out[(size_t)(n0 + a) * DM + k0 + tx * 2] = p;
  }
}

// 128x128 BK=32 BT-GEMM core (m97 structure, global_load_lds width 16)
__device__ __forceinline__ void gemm_core(
    const bf16_t* __restrict__ A, const bf16_t* __restrict__ Bt,
    f32x4 (&acc)[4][4])
{
  __shared__ __align__(16) bf16_t As[128 * 32];
  __shared__ __align__(16) bf16_t Bs[128 * 32];
  const int t = threadIdx.x, w = t >> 6, L = t & 63, quad = L >> 4, l16 = L & 15;
  const int m0 = blockIdx.x * 128, n0 = blockIdx.y * 128;
  const int mb = 64 * (w & 1), nb = 64 * (w >> 1);
  const int rowS = t >> 2, subS = (t & 3) * 8;

  for (int k0 = 0; k0 < DM; k0 += 32) {
    __syncthreads();
    glds16(&A[(size_t)(m0 + rowS) * DM + k0 + subS],       &As[t * 8]);
    glds16(&A[(size_t)(m0 + 64 + rowS) * DM + k0 + subS],  &As[2048 + t * 8]);
    glds16(&Bt[(size_t)(n0 + rowS) * DM + k0 + subS],      &Bs[t * 8]);
    glds16(&Bt[(size_t)(n0 + 64 + rowS) * DM + k0 + subS], &Bs[2048 + t * 8]);
    __syncthreads();
    bf16x8 af[4], bfr[4];
    #pragma unroll
    for (int mt = 0; mt < 4; ++mt)
      af[mt] = *(const bf16x8*)&As[(mb + 16 * mt + l16) * 32 + quad * 8];
    #pragma unroll
    for (int ct = 0; ct < 4; ++ct)
      bfr[ct] = *(const bf16x8*)&Bs[(nb + 16 * ct + l16) * 32 + quad * 8];
    #pragma unroll
    for (int mt = 0; mt < 4; ++mt)
      #pragma unroll
      for (int ct = 0; ct < 4; ++ct)
        acc[mt][ct] = __builtin_amdgcn_mfma_f32_16x16x32_bf16(af[mt], bfr[ct], acc[mt][ct], 0, 0, 0);
  }
}

// z=0: Q plain, pre-scaled by SCALE_LOG2E. z=1: K swizzled tile images. z=2: V plain.
__global__ __launch_bounds__(256) void gemm_qkv(
    const bf16_t* __restrict__ Xb, const bf16_t* __restrict__ Wt,
    const float* __restrict__ bq, const float* __restrict__ bk,
    const float* __restrict__ bv,
    bf16_t* __restrict__ Qp, bf16_t* __restrict__ Ksw, bf16_t* __restrict__ Vpl)
{
  const int z = blockIdx.z;
  const float* __restrict__ bias = (z == 0) ? bq : ((z == 1) ? bk : bv);
  f32x4 acc[4][4] = {};
  gemm_core(Xb + (size_t)z * M_ROWS * DM, Wt + (size_t)z * DM * DM, acc);

  const int t = threadIdx.x, w = t >> 6, L = t & 63, quad = L >> 4, l16 = L & 15;
  const int m0 = blockIdx.x * 128, n0 = blockIdx.y * 128;
  const int mb = 64 * (w & 1), nb = 64 * (w >> 1);
  #pragma unroll
  for (int mt = 0; mt < 4; ++mt)
    #pragma unroll
    for (int ct = 0; ct < 4; ++ct)
      #pragma unroll
      for (int r = 0; r < 4; ++r) {
        const int row = m0 + mb + 16 * mt + quad * 4 + r;
        const int n = n0 + nb + 16 * ct + l16;
        float val = acc[mt][ct][r] + bias[n];
        if (z == 0) {
          Qp[(size_t)row * DM + n] = (__bf16)(val * SCALE_LOG2E);
        } else if (z == 2) {
          Vpl[(size_t)row * DM + n] = (__bf16)val;
        } else {
          const int b_ = row >> 11, s = row & 2047, h = n >> 6, d = n & 63;
          const int bh = b_ * NH + h;
          Ksw[((size_t)bh * 32 + (s >> 6)) * 4096 + sw_off(s & 63, d)] = (__bf16)val;
        }
      }
}

// Vpl [B,S,DM] -> Vt_sw swizzled [bh][tile][image of V^T 64dv x 64key]
__global__ __launch_bounds__(256) void transpV(
    const bf16_t* __restrict__ Vpl, bf16_t* __restrict__ Vt_sw)
{
  __shared__ bf16_t Tr[64 * 72];
  const int t = threadIdx.x;
  const int key0 = blockIdx.x * 64;
  const int bh = blockIdx.y, b = bh >> 4, h = bh & 15;
  const int r = t >> 2, c = (t & 3) * 16;
  const bf16_t* src = &Vpl[(size_t)(b * S_LEN + key0 + r) * DM + h * DK + c];
  const bf16x8 v0 = *(const bf16x8*)src;
  const bf16x8 v1 = *(const bf16x8*)(src + 8);
  #pragma unroll
  for (int j = 0; j < 8; ++j) {
    Tr[r * 72 + c + j] = v0[j];
    Tr[r * 72 + c + 8 + j] = v1[j];
  }
  __syncthreads();
  const int dv = t >> 2, kc = (t & 3) * 16;
  bf16_t ov[16];
  #pragma unroll
  for (int j = 0; j < 16; ++j) ov[j] = Tr[(kc + j) * 72 + dv];
  bf16_t* dst = &Vt_sw[((size_t)bh * 32 + blockIdx.x) * 4096];
  *(bf16x8*)&dst[sw_off(dv, kc)]     = *(bf16x8*)&ov[0];
  *(bf16x8*)&dst[sw_off(dv, kc + 8)] = *(bf16x8*)&ov[8];
}

// Flash attention. Block: 128 q-rows, 4 waves = (wq x wk) 2x2:
// wave owns 64 q (2 m-tiles) x 32-key half of each 64-key tile.
// K/V double-buffered LDS (glds issued post-barrier, consumed next iter).
// P as packed q-row-pair dwords, stride-68 rows, wave-private (no P barriers).
// Masking: v_bfe_i32 sign-extend + AND. L via MFMA(P, ones). O/L reduced
// across wk pair through LDS once at the end.
__global__ __launch_bounds__(256, 2) void attn_kernel(
    const bf16_t* __restrict__ Qp, const bf16_t* __restrict__ Ksw,
    const bf16_t* __restrict__ Vt_sw, const u64* __restrict__ mbT,
    bf16_t* __restrict__ ctx)
{
  __shared__ __align__(16) bf16_t KV[4 * 4096];  // K0,K1,V0,V1 tile buffers
  __shared__ __align__(16) u32 Pd[64 * 68];      // [qpair][key], stride 68

  const int t = threadIdx.x;
  const int w = t >> 6, L = t & 63;
  const int wq = w & 1, wk = w >> 1;
  const int l31 = L & 31, h5 = L >> 5;
  const int q0 = blockIdx.x * 128;
  const int bh = blockIdx.y, b = bh >> 4, h = bh & 15;

  bf16_t* K0 = KV;            bf16_t* K1 = KV + 4096;
  bf16_t* V0 = KV + 8192;     bf16_t* V1 = KV + 12288;

  const bf16_t* KbaseG = Ksw + (size_t)bh * 32 * 4096;
  const bf16_t* VbaseG = Vt_sw + (size_t)bh * 32 * 4096;

  // Q fragments in registers (A-layout), pre-scaled by 0.125*log2e
  bf16x8 qf[2][4];
  #pragma unroll
  for (int mt = 0; mt < 2; ++mt) {
    const bf16_t* qr = &Qp[((size_t)(b * S_LEN) + q0 + 64 * wq + 32 * mt + l31) * DM + h * DK + 8 * h5];
    #pragma unroll
    for (int ks = 0; ks < 4; ++ks) qf[mt][ks] = *(const bf16x8*)&qr[16 * ks];
  }

  bf16x8 ones;
  #pragma unroll
  for (int j = 0; j < 8; ++j) ones[j] = (__bf16)1.0f;

  const int qw = 2 * blockIdx.x + wq;
  const size_t mrow = ((size_t)b * 32 + qw) * S_LEN;
  const u32 sel = (l31 & 1) ? 0x07060302u : 0x05040100u;

  f32x16 O[2][2] = {};
  f32x16 Lacc[2] = {};

  // prologue: stage tile 0 into buf0
  glds16(KbaseG + t * 8, K0 + t * 8);
  glds16(KbaseG + 2048 + t * 8, K0 + 2048 + t * 8);
  glds16(VbaseG + t * 8, V0 + t * 8);
  glds16(VbaseG + 2048 + t * 8, V0 + 2048 + t * 8);

  auto iter = [&](int kt, bf16_t* Kc, bf16_t* Vc, bf16_t* Kn, bf16_t* Vn) {
    __syncthreads();  // drains staging of tile kt; protects buffer reuse
    // mask load FIRST so its waitcnt doesn't drain the next-tile glds
    const u64 mq = mbT[mrow + (size_t)kt * 64 + 32 * wk + l31];
    if (kt + 1 < 32) {
      const bf16_t* kg = KbaseG + (size_t)(kt + 1) * 4096;
      const bf16_t* vg = VbaseG + (size_t)(kt + 1) * 4096;
      glds16(kg + t * 8, Kn + t * 8);
      glds16(kg + 2048 + t * 8, Kn + 2048 + t * 8);
      glds16(vg + t * 8, Vn + t * 8);
      glds16(vg + 2048 + t * 8, Vn + 2048 + t * 8);
    }

    // S = Q K^T : wave computes 64q x 32keys (its half)
    f32x16 sv[2] = {};
    #pragma unroll
    for (int ks = 0; ks < 4; ++ks) {
      const int ch = ((2 * ks + h5) ^ l31) & 7;
      const bf16x8 kb = *(const bf16x8*)&Kc[(32 * wk + l31) * 64 + ch * 8];
      sv[0] = __builtin_amdgcn_mfma_f32_32x32x16_bf16(qf[0][ks], kb, sv[0], 0, 0, 0);
      sv[1] = __builtin_amdgcn_mfma_f32_32x32x16_bf16(qf[1][ks], kb, sv[1], 0, 0, 0);
    }

    // softmax: p = exp2(s); mask = sign-extended bit AND; pack q-row pairs
    const u32 mlo = (u32)mq, mhi = (u32)(mq >> 32);
    #pragma unroll
    for (int mt = 0; mt < 2; ++mt) {
      const u32 mm = mt ? mhi : mlo;
      #pragma unroll
      for (int rp = 0; rp < 16; rp += 2) {
        const int c = (rp & 3) + 8 * (rp >> 2) + 4 * h5;
        const int p = 32 * wq + 16 * mt + (c >> 1);
        const float p0 = mand(__builtin_exp2f(sv[mt][rp]),     sbit(mm, c));
        const float p1 = mand(__builtin_exp2f(sv[mt][rp + 1]), sbit(mm, c + 1));
        Pd[p * 68 + 32 * wk + l31] = pack2(p0, p1);
      }
    }

    // O += P V ; Lacc += P @ ones  (P region wave-private: no barrier)
    #pragma unroll
    for (int ks = 0; ks < 2; ++ks) {
      bf16x8 pa[2];
      #pragma unroll
      for (int mt = 0; mt < 2; ++mt) {
        const int p = 32 * wq + 16 * mt + (l31 >> 1);
        const int off = p * 68 + 32 * wk + 16 * ks + 8 * h5;
        const uint4 lo = *(const uint4*)&Pd[off];
        const uint4 hi = *(const uint4*)&Pd[off + 4];
        U4B af;
        af.u.x = __builtin_amdgcn_perm(lo.y, lo.x, sel);
        af.u.y = __builtin_amdgcn_perm(lo.w, lo.z, sel);
        af.u.z = __builtin_amdgcn_perm(hi.y, hi.x, sel);
        af.u.w = __builtin_amdgcn_perm(hi.w, hi.z, sel);
        pa[mt] = af.v;
      }
      #pragma unroll
      for (int dvt = 0; dvt < 2; ++dvt) {
        const int ch = ((4 * wk + 2 * ks + h5) ^ l31) & 7;
        const bf16x8 vb = *(const bf16x8*)&Vc[(32 * dvt + l31) * 64 + ch * 8];
        O[0][dvt] = __builtin_amdgcn_mfma_f32_32x32x16_bf16(pa[0], vb, O[0][dvt], 0, 0, 0);
        O[1][dvt] = __builtin_amdgcn_mfma_f32_32x32x16_bf16(pa[1], vb, O[1][dvt], 0, 0, 0);
      }
      Lacc[0] = __builtin_amdgcn_mfma_f32_32x32x16_bf16(pa[0], ones, Lacc[0], 0, 0, 0);
      Lacc[1] = __builtin_amdgcn_mfma_f32_32x32x16_bf16(pa[1], ones, Lacc[1], 0, 0, 0);
    }
  };

  for (int kt = 0; kt < 32; kt += 2) {
    iter(kt,     K0, V0, K1, V1);
    iter(kt + 1, K1, V1, K0, V0);
  }

  // cross-wave (wk) reduction of O and L through LDS, then normalize + store
  __syncthreads();
  float* Osh = (float*)KV;   // 8192 floats = 128q x 64dv
  float* Lsh = (float*)Pd;   // 128 floats
  if (wk == 0) {
    #pragma unroll
    for (int mt = 0; mt < 2; ++mt)
      #pragma unroll
      for (int r = 0; r < 16; ++r) {
        const int ql = 64 * wq + 32 * mt + (r & 3) + 8 * (r >> 2) + 4 * h5;
        Osh[ql * 64 + l31]      = O[mt][0][r];
        Osh[ql * 64 + 32 + l31] = O[mt][1][r];
        if (l31 == 0) Lsh[ql] = Lacc[mt][r];
      }
  }
  __syncthreads();
  if (wk == 1) {
    #pragma unroll
    for (int mt = 0; mt < 2; ++mt)
      #pragma unroll
      for (int r = 0; r < 16; ++r) {
        const int ql = 64 * wq + 32 * mt + (r & 3) + 8 * (r >> 2) + 4 * h5;
        const float inv = 1.0f / (Lacc[mt][r] + Lsh[ql]);
        const size_t obase = ((size_t)(b * S_LEN) + q0 + ql) * DM + h * DK;
        ctx[obase + l31]      = (__bf16)((O[mt][0][r] + Osh[ql * 64 + l31]) * inv);
        ctx[obase + 32 + l31] = (__bf16)((O[mt][1][r] + Osh[ql * 64 + 32 + l31]) * inv);
      }
  }
}

// out = ctx @ Wo^T + bo -> fp32
__global__ __launch_bounds__(256) void gemm_out(
    const bf16_t* __restrict__ ctx, const bf16_t* __restrict__ Wto,
    const float* __restrict__ bo, float* __restrict__ out)
{
  f32x4 acc[4][4] = {};
  gemm_core(ctx, Wto, acc);
  const int t = threadIdx.x, w = t >> 6, L = t & 63, quad = L >> 4, l16 = L & 15;
  const int m0 = blockIdx.x * 128, n0 = blockIdx.y * 128;
  const int mb = 64 * (w & 1), nb = 64 * (w >> 1);
  #pragma unroll
  for (int mt = 0; mt < 4; ++mt)
    #pragma unroll
    for (int ct = 0; ct < 4; ++ct)
      #pragma unroll
      for (int r = 0; r < 4; ++r) {
        const int row = m0 + mb + 16 * mt + quad * 4 + r;
        const int n = n0 + nb + 16 * ct + l16;
        out[(size_t)row * DM + n] = acc[mt][ct][r] + bo[n];
      }
}

extern "C" void kernel_launch(void* const* d_in, const int* in_sizes, int n_in,
                              void* d_out, int out_size, void* d_ws, size_t ws_size,
                              hipStream_t stream) {
  const float* q  = (const float*)d_in[0];
  const float* k  = (const float*)d_in[1];
  const float* v  = (const float*)d_in[2];
  const int* mask = (const int*)d_in[3];
  const float* Wq = (const float*)d_in[4];
  const float* bq = (const float*)d_in[5];
  const float* Wk = (const float*)d_in[6];
  const float* bk = (const float*)d_in[7];
  const float* Wv = (const float*)d_in[8];
  const float* bv = (const float*)d_in[9];
  const float* Wo = (const float*)d_in[10];
  const float* bo = (const float*)d_in[11];
  float* out = (float*)d_out;

  const size_t SLICE = (size_t)M_ROWS * DM;  // 4.19M bf16 elems = 8 MB
  bf16_t* ws_b = (bf16_t*)d_ws;
  bf16_t* Xb    = ws_b;                // 3 SLICE; dead after gemm_qkv
  bf16_t* Qp    = ws_b + 3 * SLICE;    // plain, pre-scaled
  bf16_t* Ksw   = ws_b + 4 * SLICE;    // swizzled K tiles
  bf16_t* Vpl   = ws_b + 5 * SLICE;    // plain V
  bf16_t* Wt    = ws_b + 6 * SLICE;    // 4x1024x1024 = 1 SLICE
  u64* mbT      = (u64*)(ws_b + 7 * SLICE);           // 1 MB
  bf16_t* Vt_sw = ws_b + 2 * SLICE;    // alias Xb slice 2 (dead after gemm_qkv)
  bf16_t* ctx   = ws_b;                // alias Xb slice 0

  pack_maskT<<<dim3(128), dim3(256), 0, stream>>>(mask, mbT);
  cvt_inputs<<<dim3(2048, 3), dim3(256), 0, stream>>>(q, k, v, Xb);
  transw_kernel<<<dim3(16, 16, 4), dim3(256), 0, stream>>>(Wq, Wk, Wv, Wo, Wt);
  gemm_qkv<<<dim3(32, 8, 3), dim3(256), 0, stream>>>(Xb, Wt, bq, bk, bv, Qp, Ksw, Vpl);
  transpV<<<dim3(32, 32), dim3(256), 0, stream>>>(Vpl, Vt_sw);
  attn_kernel<<<dim3(16, 32), dim3(256), 0, stream>>>(Qp, Ksw, Vt_sw, mbT, ctx);
  gemm_out<<<dim3(32, 8), dim3(256), 0, stream>>>(ctx, Wt + (size_t)3 * DM * DM, bo, out);
}

// Round 6
// 293.684 us; speedup vs baseline: 1.1899x; 1.0328x over previous
//
#include <hip/hip_runtime.h>
#include <hip/hip_bf16.h>

typedef __bf16 bf16_t;
typedef __bf16 bf16x2 __attribute__((ext_vector_type(2)));
typedef __bf16 bf16x8 __attribute__((ext_vector_type(8)));
typedef float f32x4 __attribute__((ext_vector_type(4)));
typedef float f32x16 __attribute__((ext_vector_type(16)));
typedef unsigned int u32;
typedef unsigned long long u64;

#define S_LEN 2048
#define DM 1024
#define NH 16
#define DK 64
#define M_ROWS 4096
#define SCALE_LOG2E 0.1803368801111204f /* 0.125 * log2(e) */

// 64-col bf16 tile image: 8 chunks of 8 elems; phys chunk = chunk ^ (row&7).
__device__ __forceinline__ int sw_off(int row, int col) {
  return row * 64 + ((((col >> 3) ^ row) & 7) << 3) + (col & 7);
}

__device__ __forceinline__ bf16x8 cvt8(const float4& a, const float4& b) {
  bf16x8 v;
  v[0] = (__bf16)a.x; v[1] = (__bf16)a.y; v[2] = (__bf16)a.z; v[3] = (__bf16)a.w;
  v[4] = (__bf16)b.x; v[5] = (__bf16)b.y; v[6] = (__bf16)b.z; v[7] = (__bf16)b.w;
  return v;
}

__device__ __forceinline__ void glds16(const bf16_t* g, bf16_t* l) {
  __builtin_amdgcn_global_load_lds(
      (const __attribute__((address_space(1))) void*)g,
      (__attribute__((address_space(3))) void*)l, 16, 0, 0);
}

__device__ __forceinline__ u32 sbit(u32 m, int c) {
  return (u32)(((int)(m << (31 - c))) >> 31);
}
__device__ __forceinline__ float mand(float p, u32 e) {
  return __builtin_bit_cast(float, __builtin_bit_cast(u32, p) & e);
}
__device__ __forceinline__ u32 pack2(float lo, float hi) {
#if __has_builtin(__builtin_amdgcn_cvt_pk_bf16_f32)
  bf16x2 r = __builtin_amdgcn_cvt_pk_bf16_f32(lo, hi);
  return __builtin_bit_cast(u32, r);
#else
  union { __bf16 h[2]; u32 u; } x;
  x.h[0] = (__bf16)lo; x.h[1] = (__bf16)hi;
  return x.u;
#endif
}

union U4B { uint4 u; bf16x8 v; };

#define PREP_PACK_BLOCKS 8192
#define PREP_CVT_BLOCKS  6144
#define PREP_TW_BLOCKS   1024

// Fused prep: [0,8192) row-packed mask ballot; [8192,14336) fp32->bf16 cvt;
// [14336,15360) W transpose->bf16.
__global__ __launch_bounds__(256) void prep_kernel(
    const int* __restrict__ mask,
    const float* __restrict__ q, const float* __restrict__ k, const float* __restrict__ v,
    const float* __restrict__ Wq, const float* __restrict__ Wk,
    const float* __restrict__ Wv, const float* __restrict__ Wo,
    u64* __restrict__ mrowT, bf16_t* __restrict__ Xb, bf16_t* __restrict__ Wt)
{
  __shared__ float tile[64][65];
  const int bx = blockIdx.x;
  if (bx < PREP_PACK_BLOCKS) {
    // mask int32 [B,1,S,S] -> mrowT[b][kw][q], bit i = mask[b][q][kw*64+i]
    const int gw = (bx * 256 + threadIdx.x) >> 6;  // wave id: b(1)|q(11)|kwg(3)
    const int lane = threadIdx.x & 63;
    const int kw0 = (gw & 7) * 4;
    const int qr = (gw >> 3) & 2047;
    const int b = gw >> 14;
    #pragma unroll
    for (int j = 0; j < 4; ++j) {
      const int kw = kw0 + j;
      const int mv = mask[((size_t)b * S_LEN + qr) * S_LEN + kw * 64 + lane];
      const u64 bits = __ballot(mv != 0);
      if (lane == 0) mrowT[((size_t)b * 32 + kw) * S_LEN + qr] = bits;
    }
  } else if (bx < PREP_PACK_BLOCKS + PREP_CVT_BLOCKS) {
    const int id = bx - PREP_PACK_BLOCKS;
    const int z = id >> 11, blk = id & 2047;
    const float* __restrict__ src = (z == 0) ? q : ((z == 1) ? k : v);
    const size_t idx = ((size_t)blk * 256 + threadIdx.x) * 8;
    const float4 a = *(const float4*)&src[idx];
    const float4 b4 = *(const float4*)&src[idx + 4];
    *(bf16x8*)&Xb[(size_t)z * M_ROWS * DM + idx] = cvt8(a, b4);
  } else {
    const int id = bx - (PREP_PACK_BLOCKS + PREP_CVT_BLOCKS);
    const int z = id >> 8, rem = id & 255;
    const float* __restrict__ W = (z == 0) ? Wq : ((z == 1) ? Wk : ((z == 2) ? Wv : Wo));
    bf16_t* __restrict__ out = Wt + (size_t)z * DM * DM;
    const int tx = threadIdx.x & 31, ty = threadIdx.x >> 5;
    const int k0 = (rem >> 4) * 64, n0 = (rem & 15) * 64;
    #pragma unroll
    for (int j = 0; j < 8; ++j) {
      const float2 vv = *(const float2*)&W[(size_t)(k0 + ty + 8 * j) * DM + n0 + tx * 2];
      tile[ty + 8 * j][tx * 2] = vv.x;
      tile[ty + 8 * j][tx * 2 + 1] = vv.y;
    }
    __syncthreads();
    #pragma unroll
    for (int j = 0; j < 8; ++j) {
      const int a = ty + 8 * j;
      bf16x2 p;
      p[0] = (__bf16)tile[tx * 2][a];
      p[1] = (__bf16)tile[tx * 2 + 1][a];
      *(bf16x2*)&out[(size_t)(n0 + a) * DM + k0 + tx * 2] = p;
    }
  }
}

// 128x128 BK=32 BT-GEMM core (m97 structure, global_load_lds width 16)
__device__ __forceinline__ void gemm_core(
    const bf16_t* __restrict__ A, const bf16_t* __restrict__ Bt,
    f32x4 (&acc)[4][4])
{
  __shared__ __align__(16) bf16_t As[128 * 32];
  __shared__ __align__(16) bf16_t Bs[128 * 32];
  const int t = threadIdx.x, w = t >> 6, L = t & 63, quad = L >> 4, l16 = L & 15;
  const int m0 = blockIdx.x * 128, n0 = blockIdx.y * 128;
  const int mb = 64 * (w & 1), nb = 64 * (w >> 1);
  const int rowS = t >> 2, subS = (t & 3) * 8;

  for (int k0 = 0; k0 < DM; k0 += 32) {
    __syncthreads();
    glds16(&A[(size_t)(m0 + rowS) * DM + k0 + subS],       &As[t * 8]);
    glds16(&A[(size_t)(m0 + 64 + rowS) * DM + k0 + subS],  &As[2048 + t * 8]);
    glds16(&Bt[(size_t)(n0 + rowS) * DM + k0 + subS],      &Bs[t * 8]);
    glds16(&Bt[(size_t)(n0 + 64 + rowS) * DM + k0 + subS], &Bs[2048 + t * 8]);
    __syncthreads();
    bf16x8 af[4], bfr[4];
    #pragma unroll
    for (int mt = 0; mt < 4; ++mt)
      af[mt] = *(const bf16x8*)&As[(mb + 16 * mt + l16) * 32 + quad * 8];
    #pragma unroll
    for (int ct = 0; ct < 4; ++ct)
      bfr[ct] = *(const bf16x8*)&Bs[(nb + 16 * ct + l16) * 32 + quad * 8];
    #pragma unroll
    for (int mt = 0; mt < 4; ++mt)
      #pragma unroll
      for (int ct = 0; ct < 4; ++ct)
        acc[mt][ct] = __builtin_amdgcn_mfma_f32_16x16x32_bf16(af[mt], bfr[ct], acc[mt][ct], 0, 0, 0);
  }
}

// z=0: Q plain, pre-scaled by SCALE_LOG2E. z=1: K swizzled tile images. z=2: V plain.
__global__ __launch_bounds__(256) void gemm_qkv(
    const bf16_t* __restrict__ Xb, const bf16_t* __restrict__ Wt,
    const float* __restrict__ bq, const float* __restrict__ bk,
    const float* __restrict__ bv,
    bf16_t* __restrict__ Qp, bf16_t* __restrict__ Ksw, bf16_t* __restrict__ Vpl)
{
  const int z = blockIdx.z;
  const float* __restrict__ bias = (z == 0) ? bq : ((z == 1) ? bk : bv);
  f32x4 acc[4][4] = {};
  gemm_core(Xb + (size_t)z * M_ROWS * DM, Wt + (size_t)z * DM * DM, acc);

  const int t = threadIdx.x, w = t >> 6, L = t & 63, quad = L >> 4, l16 = L & 15;
  const int m0 = blockIdx.x * 128, n0 = blockIdx.y * 128;
  const int mb = 64 * (w & 1), nb = 64 * (w >> 1);
  #pragma unroll
  for (int mt = 0; mt < 4; ++mt)
    #pragma unroll
    for (int ct = 0; ct < 4; ++ct)
      #pragma unroll
      for (int r = 0; r < 4; ++r) {
        const int row = m0 + mb + 16 * mt + quad * 4 + r;
        const int n = n0 + nb + 16 * ct + l16;
        float val = acc[mt][ct][r] + bias[n];
        if (z == 0) {
          Qp[(size_t)row * DM + n] = (__bf16)(val * SCALE_LOG2E);
        } else if (z == 2) {
          Vpl[(size_t)row * DM + n] = (__bf16)val;
        } else {
          const int b_ = row >> 11, s = row & 2047, h = n >> 6, d = n & 63;
          const int bh = b_ * NH + h;
          Ksw[((size_t)bh * 32 + (s >> 6)) * 4096 + sw_off(s & 63, d)] = (__bf16)val;
        }
      }
}

// Vpl [B,S,DM] -> Vt_sw swizzled [bh][tile][image of V^T 64dv x 64key]
__global__ __launch_bounds__(256) void transpV(
    const bf16_t* __restrict__ Vpl, bf16_t* __restrict__ Vt_sw)
{
  __shared__ bf16_t Tr[64 * 72];
  const int t = threadIdx.x;
  const int key0 = blockIdx.x * 64;
  const int bh = blockIdx.y, b = bh >> 4, h = bh & 15;
  const int r = t >> 2, c = (t & 3) * 16;
  const bf16_t* src = &Vpl[(size_t)(b * S_LEN + key0 + r) * DM + h * DK + c];
  const bf16x8 v0 = *(const bf16x8*)src;
  const bf16x8 v1 = *(const bf16x8*)(src + 8);
  #pragma unroll
  for (int j = 0; j < 8; ++j) {
    Tr[r * 72 + c + j] = v0[j];
    Tr[r * 72 + c + 8 + j] = v1[j];
  }
  __syncthreads();
  const int dv = t >> 2, kc = (t & 3) * 16;
  bf16_t ov[16];
  #pragma unroll
  for (int j = 0; j < 16; ++j) ov[j] = Tr[(kc + j) * 72 + dv];
  bf16_t* dst = &Vt_sw[((size_t)bh * 32 + blockIdx.x) * 4096];
  *(bf16x8*)&dst[sw_off(dv, kc)]     = *(bf16x8*)&ov[0];
  *(bf16x8*)&dst[sw_off(dv, kc + 8)] = *(bf16x8*)&ov[8];
}

// Flash attention, transposed-score form. Block: 64 q-rows, 2 waves (wk 0/1).
// Wave: 64q x 32keys. S^T = mfma(K_A, Q_B) -> lane=query, regs=keys.
// P relayout: pack key-pairs -> bf16 dwords, shfl_xor(32) h5 exchange,
// cndmask assemble -> P as B-operand. O^T = mfma(V_A, P_B). l = per-lane
// reg sums. No P LDS traffic. K/V double-buffered via global_load_lds;
// mask prefetched one tile ahead, issued BEFORE the glds batch.
__global__ __launch_bounds__(128, 2) void attn_kernel(
    const bf16_t* __restrict__ Qp, const bf16_t* __restrict__ Ksw,
    const bf16_t* __restrict__ Vt_sw, const u64* __restrict__ mrowT,
    bf16_t* __restrict__ ctx)
{
  __shared__ __align__(16) bf16_t KV[4 * 4096];  // K0,K1,V0,V1 (32 KB)

  const int t = threadIdx.x;
  const int wk = t >> 6, L = t & 63;
  const int l31 = L & 31, h5 = L >> 5;
  const int q0 = blockIdx.x * 64;
  const int bh = blockIdx.y, b = bh >> 4, h = bh & 15;

  bf16_t* K0 = KV;        bf16_t* K1 = KV + 4096;
  bf16_t* V0 = KV + 8192; bf16_t* V1 = KV + 12288;

  const bf16_t* KbaseG = Ksw + (size_t)bh * 32 * 4096;
  const bf16_t* VbaseG = Vt_sw + (size_t)bh * 32 * 4096;

  // Q B-frags in registers: queries q0 + 32*qb + l31 (pre-scaled in gemm_qkv)
  bf16x8 qf[2][4];
  #pragma unroll
  for (int qb = 0; qb < 2; ++qb) {
    const bf16_t* qr = &Qp[((size_t)(b * S_LEN) + q0 + 32 * qb + l31) * DM + h * DK + 8 * h5];
    #pragma unroll
    for (int ks = 0; ks < 4; ++ks) qf[qb][ks] = *(const bf16x8*)&qr[16 * ks];
  }

  const u64* mbase = &mrowT[(size_t)b * 32 * S_LEN + q0 + l31];

  f32x16 O[2][2] = {};   // [qb][dvb], lane=query, regs=dv
  float lacc[2] = {0.f, 0.f};

  auto stage = [&](int kt, bf16_t* Kd, bf16_t* Vd) {
    const bf16_t* kg = KbaseG + (size_t)kt * 4096;
    const bf16_t* vg = VbaseG + (size_t)kt * 4096;
    #pragma unroll
    for (int i = 0; i < 4; ++i) glds16(kg + i * 1024 + t * 8, Kd + i * 1024 + t * 8);
    #pragma unroll
    for (int i = 0; i < 4; ++i) glds16(vg + i * 1024 + t * 8, Vd + i * 1024 + t * 8);
  };

  // prologue
  u64 mp0 = mbase[0], mp1 = mbase[32];
  stage(0, K0, V0);

  auto iter = [&](int kt, bf16_t* Kc, bf16_t* Vc, bf16_t* Kn, bf16_t* Vn) {
    __syncthreads();  // drains staging of tile kt
    const u64 mq0 = mp0, mq1 = mp1;
    if (kt + 1 < 32) {
      // mask prefetch FIRST (older in VM queue -> waiting on it won't drain glds)
      mp0 = mbase[(size_t)(kt + 1) * S_LEN];
      mp1 = mbase[(size_t)(kt + 1) * S_LEN + 32];
      stage(kt + 1, Kn, Vn);
    }

    // S^T = K(A) x Q(B): lane = query, regs = keys of this wave's 32wk half
    f32x16 sv[2] = {};
    #pragma unroll
    for (int ks = 0; ks < 4; ++ks) {
      const int ch = ((2 * ks + h5) ^ l31) & 7;
      const bf16x8 kb = *(const bf16x8*)&Kc[(32 * wk + l31) * 64 + ch * 8];
      sv[0] = __builtin_amdgcn_mfma_f32_32x32x16_bf16(kb, qf[0][ks], sv[0], 0, 0, 0);
      sv[1] = __builtin_amdgcn_mfma_f32_32x32x16_bf16(kb, qf[1][ks], sv[1], 0, 0, 0);
    }

    // softmax + register relayout into B-operand fragments
    u32 fr[2][2][4];  // [qb][ks][dword]
    #pragma unroll
    for (int qb = 0; qb < 2; ++qb) {
      const u32 mh = (u32)((qb ? mq1 : mq0) >> (32 * wk));
      float p[16];
      #pragma unroll
      for (int r = 0; r < 16; ++r) {
        const int bit = (r & 3) + 8 * (r >> 2) + 4 * h5;
        p[r] = mand(__builtin_exp2f(sv[qb][r]), sbit(mh, bit));
      }
      lacc[qb] += ((p[0] + p[1]) + (p[2] + p[3])) + ((p[4] + p[5]) + (p[6] + p[7]))
                + ((p[8] + p[9]) + (p[10] + p[11])) + ((p[12] + p[13]) + (p[14] + p[15]));
      u32 D[8];
      #pragma unroll
      for (int j = 0; j < 8; ++j) D[j] = pack2(p[2 * j], p[2 * j + 1]);
      // h5 exchange: send what the partner needs, receive what we need
      const u32 S0 = h5 ? D[0] : D[2];
      const u32 S1 = h5 ? D[1] : D[3];
      const u32 S2 = h5 ? D[4] : D[6];
      const u32 S3 = h5 ? D[5] : D[7];
      const u32 R0 = (u32)__shfl_xor((int)S0, 32);
      const u32 R1 = (u32)__shfl_xor((int)S1, 32);
      const u32 R2 = (u32)__shfl_xor((int)S2, 32);
      const u32 R3 = (u32)__shfl_xor((int)S3, 32);
      fr[qb][0][0] = h5 ? R0 : D[0];
      fr[qb][0][1] = h5 ? R1 : D[1];
      fr[qb][0][2] = h5 ? D[2] : R0;
      fr[qb][0][3] = h5 ? D[3] : R1;
      fr[qb][1][0] = h5 ? R2 : D[4];
      fr[qb][1][1] = h5 ? R3 : D[5];
      fr[qb][1][2] = h5 ? D[6] : R2;
      fr[qb][1][3] = h5 ? D[7] : R3;
    }

    // O^T += V(A) x P(B)
    #pragma unroll
    for (int ks = 0; ks < 2; ++ks) {
      U4B pf0, pf1;
      pf0.u = *(uint4*)fr[0][ks];
      pf1.u = *(uint4*)fr[1][ks];
      #pragma unroll
      for (int dvb = 0; dvb < 2; ++dvb) {
        const int ch = ((4 * wk + 2 * ks + h5) ^ l31) & 7;
        const bf16x8 vb = *(const bf16x8*)&Vc[(32 * dvb + l31) * 64 + ch * 8];
        O[0][dvb] = __builtin_amdgcn_mfma_f32_32x32x16_bf16(vb, pf0.v, O[0][dvb], 0, 0, 0);
        O[1][dvb] = __builtin_amdgcn_mfma_f32_32x32x16_bf16(vb, pf1.v, O[1][dvb], 0, 0, 0);
      }
    }
  };

  for (int kt = 0; kt < 32; kt += 2) {
    iter(kt,     K0, V0, K1, V1);
    iter(kt + 1, K1, V1, K0, V0);
  }

  // epilogue: cross-wk sum + normalize + transpose to row-major via LDS
  __syncthreads();
  u32* OshU = (u32*)KV;                   // [64][36] dwords (9216 B)
  float* Lsh = (float*)(OshU + 64 * 36);  // 64 floats
  if (wk == 0) {
    #pragma unroll
    for (int qb = 0; qb < 2; ++qb) {
      const float ls = lacc[qb] + __shfl_xor(lacc[qb], 32);
      if (h5 == 0) Lsh[32 * qb + l31] = ls;
      #pragma unroll
      for (int dvb = 0; dvb < 2; ++dvb)
        #pragma unroll
        for (int r = 0; r < 16; r += 2) {
          const int col = 16 * dvb + ((r & 3) >> 1) + 4 * (r >> 2) + 2 * h5;
          OshU[(32 * qb + l31) * 36 + col] = pack2(O[qb][dvb][r], O[qb][dvb][r + 1]);
        }
    }
  }
  __syncthreads();
  if (wk == 1) {
    #pragma unroll
    for (int qb = 0; qb < 2; ++qb) {
      const float ls = lacc[qb] + __shfl_xor(lacc[qb], 32) + Lsh[32 * qb + l31];
      const float inv = 1.0f / ls;
      #pragma unroll
      for (int dvb = 0; dvb < 2; ++dvb)
        #pragma unroll
        for (int r = 0; r < 16; r += 2) {
          const int col = 16 * dvb + ((r & 3) >> 1) + 4 * (r >> 2) + 2 * h5;
          const u32 d = OshU[(32 * qb + l31) * 36 + col];
          const float a0 = __builtin_bit_cast(float, d << 16);
          const float a1 = __builtin_bit_cast(float, d & 0xffff0000u);
          OshU[(32 * qb + l31) * 36 + col] =
              pack2((a0 + O[qb][dvb][r]) * inv, (a1 + O[qb][dvb][r + 1]) * inv);
        }
    }
  }
  __syncthreads();
  {
    const int qr = t >> 1, half = t & 1;
    const u32* src = &OshU[qr * 36 + 16 * half];
    const uint4 x0 = *(const uint4*)&src[0];
    const uint4 x1 = *(const uint4*)&src[4];
    const uint4 x2 = *(const uint4*)&src[8];
    const uint4 x3 = *(const uint4*)&src[12];
    bf16_t* dst = &ctx[((size_t)(b * S_LEN) + q0 + qr) * DM + h * DK + 32 * half];
    *(uint4*)&dst[0]  = x0;
    *(uint4*)&dst[8]  = x1;
    *(uint4*)&dst[16] = x2;
    *(uint4*)&dst[24] = x3;
  }
}

// out = ctx @ Wo^T + bo -> fp32
__global__ __launch_bounds__(256) void gemm_out(
    const bf16_t* __restrict__ ctx, const bf16_t* __restrict__ Wto,
    const float* __restrict__ bo, float* __restrict__ out)
{
  f32x4 acc[4][4] = {};
  gemm_core(ctx, Wto, acc);
  const int t = threadIdx.x, w = t >> 6, L = t & 63, quad = L >> 4, l16 = L & 15;
  const int m0 = blockIdx.x * 128, n0 = blockIdx.y * 128;
  const int mb = 64 * (w & 1), nb = 64 * (w >> 1);
  #pragma unroll
  for (int mt = 0; mt < 4; ++mt)
    #pragma unroll
    for (int ct = 0; ct < 4; ++ct)
      #pragma unroll
      for (int r = 0; r < 4; ++r) {
        const int row = m0 + mb + 16 * mt + quad * 4 + r;
        const int n = n0 + nb + 16 * ct + l16;
        out[(size_t)row * DM + n] = acc[mt][ct][r] + bo[n];
      }
}

extern "C" void kernel_launch(void* const* d_in, const int* in_sizes, int n_in,
                              void* d_out, int out_size, void* d_ws, size_t ws_size,
                              hipStream_t stream) {
  const float* q  = (const float*)d_in[0];
  const float* k  = (const float*)d_in[1];
  const float* v  = (const float*)d_in[2];
  const int* mask = (const int*)d_in[3];
  const float* Wq = (const float*)d_in[4];
  const float* bq = (const float*)d_in[5];
  const float* Wk = (const float*)d_in[6];
  const float* bk = (const float*)d_in[7];
  const float* Wv = (const float*)d_in[8];
  const float* bv = (const float*)d_in[9];
  const float* Wo = (const float*)d_in[10];
  const float* bo = (const float*)d_in[11];
  float* out = (float*)d_out;

  const size_t SLICE = (size_t)M_ROWS * DM;  // 4.19M bf16 elems = 8 MB
  bf16_t* ws_b = (bf16_t*)d_ws;
  bf16_t* Xb    = ws_b;                // 3 SLICE; dead after gemm_qkv
  bf16_t* Qp    = ws_b + 3 * SLICE;    // plain, pre-scaled
  bf16_t* Ksw   = ws_b + 4 * SLICE;    // swizzled K tile images
  bf16_t* Vpl   = ws_b + 5 * SLICE;    // plain V
  bf16_t* Wt    = ws_b + 6 * SLICE;    // 4x1024x1024
  u64* mrowT    = (u64*)(ws_b + 7 * SLICE);  // 1 MB
  bf16_t* Vt_sw = ws_b + 2 * SLICE;    // alias Xb slice 2
  bf16_t* ctx   = ws_b;                // alias Xb slice 0

  prep_kernel<<<dim3(PREP_PACK_BLOCKS + PREP_CVT_BLOCKS + PREP_TW_BLOCKS),
                dim3(256), 0, stream>>>(mask, q, k, v, Wq, Wk, Wv, Wo, mrowT, Xb, Wt);
  gemm_qkv<<<dim3(32, 8, 3), dim3(256), 0, stream>>>(Xb, Wt, bq, bk, bv, Qp, Ksw, Vpl);
  transpV<<<dim3(32, 32), dim3(256), 0, stream>>>(Vpl, Vt_sw);
  attn_kernel<<<dim3(32, 32), dim3(128), 0, stream>>>(Qp, Ksw, Vt_sw, mrowT, ctx);
  gemm_out<<<dim3(32, 8), dim3(256), 0, stream>>>(ctx, Wt + (size_t)3 * DM * DM, bo, out);
}